// Round 16
// baseline (497.821 us; speedup 1.0000x reference)
//
#include <hip/hip_runtime.h>
#include <math.h>

#define NN 100000
#define NE 1600000
#define INC 128
#define OC 64
#define ED 32

typedef __attribute__((ext_vector_type(8))) short bf16x8;
typedef __attribute__((ext_vector_type(4))) float f32x4;

__device__ __forceinline__ float sigmoidf_(float z) {
    return __builtin_amdgcn_rcpf(1.0f + __expf(-z));
}

__device__ __forceinline__ unsigned short f2bf(float x) {
    unsigned int u = __float_as_uint(x);
    unsigned int r = u + 0x7FFFu + ((u >> 16) & 1u);
    return (unsigned short)(r >> 16);
}
__device__ __forceinline__ float bf2f(unsigned short u) {
    return __uint_as_float((unsigned int)u << 16);
}
__device__ __forceinline__ unsigned cvtpk(float lo, float hi) {
    unsigned r;
    asm("v_cvt_pk_bf16_f32 %0, %1, %2" : "=v"(r) : "v"(lo), "v"(hi));
    return r;
}

__device__ __forceinline__ unsigned long long pack_ec(int r, int cl, int e) {
    return ((unsigned long long)(unsigned)r << 47) |
           ((unsigned long long)(unsigned)cl << 30) | (unsigned)e;
}

// K0: weight prep.
extern "C" __global__ void __launch_bounds__(256)
k_wfuse(const float* __restrict__ We, const float* __restrict__ be,
        const float* __restrict__ Wg, const float* __restrict__ Wl,
        const float* __restrict__ Wr, unsigned short* __restrict__ WfT,
        unsigned short* __restrict__ WeT, float* __restrict__ hb,
        unsigned short* __restrict__ WlrT) {
    int idx = blockIdx.x * 256 + threadIdx.x;
    if (idx < ED * OC) {
        int ch = idx >> 5, d = idx & 31;
        float acc = 0.0f;
#pragma unroll
        for (int k = 0; k < OC; ++k)
            acc = fmaf(We[d * OC + k], Wg[(OC + k) * OC + ch], acc);
        WfT[idx] = f2bf(acc);
    } else if (idx < 2 * ED * OC) {
        int i2 = idx - ED * OC;
        int ch = i2 >> 5, d = i2 & 31;
        WeT[i2] = f2bf(We[d * OC + ch]);
    } else if (idx < 2 * ED * OC + OC) {
        int j = idx - 2 * ED * OC;
        float acc = 0.0f;
#pragma unroll
        for (int k = 0; k < OC; ++k)
            acc = fmaf(be[k], Wg[(OC + k) * OC + j], acc);
        hb[j] = acc;
    } else if (idx < 2 * ED * OC + OC + 2 * INC * OC) {
        int i3 = idx - (2 * ED * OC + OC);
        int ch = i3 >> 7, k = i3 & 127;
        float v = (ch < OC) ? Wl[k * OC + ch] : Wr[k * OC + (ch - OC)];
        WlrT[i3] = f2bf(v);
    }
}

// K1: MFMA GEMM [yl | xwr](bf16) = x @ [Wl | Wr], hist fused (fire-and-forget).
extern "C" __global__ void __launch_bounds__(256)
k_xw(const float* __restrict__ x, const unsigned short* __restrict__ WlrT,
     unsigned short* __restrict__ ybf, unsigned short* __restrict__ xwrbf,
     const int* __restrict__ colv, int* __restrict__ cnti) {
    int t = threadIdx.x;
    {
        int eb = (blockIdx.x * 256 + t) * 4;
        if (eb + 3 < NE) {
            int4 cv = *reinterpret_cast<const int4*>(colv + eb);
            int c0 = min(max(cv.x, 0), NN - 1);
            int c1 = min(max(cv.y, 0), NN - 1);
            int c2 = min(max(cv.z, 0), NN - 1);
            int c3 = min(max(cv.w, 0), NN - 1);
            atomicAdd(&cnti[c0], 1);
            atomicAdd(&cnti[c1], 1);
            atomicAdd(&cnti[c2], 1);
            atomicAdd(&cnti[c3], 1);
        }
    }

    __shared__ unsigned short xs[64][136];
    int base = blockIdx.x * 64;
    {
        int rr = t >> 2, cc = (t & 3) * 32;
        int grow = base + rr;
        if (grow < NN) {
            const float4* xp = reinterpret_cast<const float4*>(
                x + (size_t)grow * INC + cc);
#pragma unroll
            for (int q = 0; q < 8; ++q) {
                float4 v = xp[q];
                uint2 uv;
                uv.x = cvtpk(v.x, v.y);
                uv.y = cvtpk(v.z, v.w);
                *reinterpret_cast<uint2*>(&xs[rr][cc + q * 4]) = uv;
            }
        } else {
#pragma unroll
            for (int q = 0; q < 8; ++q) {
                uint2 uv; uv.x = 0u; uv.y = 0u;
                *reinterpret_cast<uint2*>(&xs[rr][cc + q * 4]) = uv;
            }
        }
    }
    __syncthreads();

    int lane = t & 63, w = t >> 6;
    int c = lane & 15, g = lane >> 4;

    bf16x8 bw0[4], bw1[4];
#pragma unroll
    for (int kk = 0; kk < 4; ++kk) {
        bw0[kk] = *reinterpret_cast<const bf16x8*>(
            WlrT + (w * 32 + 0 * 16 + c) * INC + kk * 32 + g * 8);
        bw1[kk] = *reinterpret_cast<const bf16x8*>(
            WlrT + (w * 32 + 1 * 16 + c) * INC + kk * 32 + g * 8);
    }

    f32x4 acc[4][2];
#pragma unroll
    for (int mt = 0; mt < 4; ++mt)
#pragma unroll
        for (int nt = 0; nt < 2; ++nt)
            acc[mt][nt] = (f32x4){0.0f, 0.0f, 0.0f, 0.0f};

#pragma unroll
    for (int kk = 0; kk < 4; ++kk) {
        bf16x8 a0 = *reinterpret_cast<const bf16x8*>(&xs[0 * 16 + c][kk * 32 + g * 8]);
        bf16x8 a1 = *reinterpret_cast<const bf16x8*>(&xs[1 * 16 + c][kk * 32 + g * 8]);
        bf16x8 a2 = *reinterpret_cast<const bf16x8*>(&xs[2 * 16 + c][kk * 32 + g * 8]);
        bf16x8 a3 = *reinterpret_cast<const bf16x8*>(&xs[3 * 16 + c][kk * 32 + g * 8]);
        acc[0][0] = __builtin_amdgcn_mfma_f32_16x16x32_bf16(a0, bw0[kk], acc[0][0], 0, 0, 0);
        acc[0][1] = __builtin_amdgcn_mfma_f32_16x16x32_bf16(a0, bw1[kk], acc[0][1], 0, 0, 0);
        acc[1][0] = __builtin_amdgcn_mfma_f32_16x16x32_bf16(a1, bw0[kk], acc[1][0], 0, 0, 0);
        acc[1][1] = __builtin_amdgcn_mfma_f32_16x16x32_bf16(a1, bw1[kk], acc[1][1], 0, 0, 0);
        acc[2][0] = __builtin_amdgcn_mfma_f32_16x16x32_bf16(a2, bw0[kk], acc[2][0], 0, 0, 0);
        acc[2][1] = __builtin_amdgcn_mfma_f32_16x16x32_bf16(a2, bw1[kk], acc[2][1], 0, 0, 0);
        acc[3][0] = __builtin_amdgcn_mfma_f32_16x16x32_bf16(a3, bw0[kk], acc[3][0], 0, 0, 0);
        acc[3][1] = __builtin_amdgcn_mfma_f32_16x16x32_bf16(a3, bw1[kk], acc[3][1], 0, 0, 0);
    }

#pragma unroll
    for (int mt = 0; mt < 4; ++mt) {
#pragma unroll
        for (int nt = 0; nt < 2; ++nt) {
            int ch = w * 32 + nt * 16 + c;
#pragma unroll
            for (int j = 0; j < 4; ++j) {
                int row = base + mt * 16 + g * 4 + j;
                if (row < NN) {
                    unsigned short vb = f2bf(acc[mt][nt][j]);
                    if (ch < OC) ybf[(size_t)row * OC + ch] = vb;
                    else         xwrbf[(size_t)row * OC + (ch - OC)] = vb;
                }
            }
        }
    }
}

extern "C" __global__ void __launch_bounds__(1024)
k_scanA(const int* __restrict__ cnti, int* __restrict__ cur,
        int* __restrict__ bsum) {
    __shared__ int s[1024];
    int t = threadIdx.x;
    int idx = blockIdx.x * 1024 + t;
    int v = (idx < NN) ? cnti[idx] : 0;
    s[t] = v;
    __syncthreads();
#pragma unroll
    for (int off = 1; off < 1024; off <<= 1) {
        int tmp = (t >= off) ? s[t - off] : 0;
        __syncthreads();
        s[t] += tmp;
        __syncthreads();
    }
    if (idx < NN) cur[idx] = s[t] - v;
    if (t == 1023) bsum[blockIdx.x] = s[1023];
}

// scanB: scan the 98 block sums (exclusive) AND produce gcur256.
extern "C" __global__ void __launch_bounds__(256)
k_scanB(int* __restrict__ bsum, const int* __restrict__ cur,
        int* __restrict__ gcur256) {
    __shared__ int s[256];
    int t = threadIdx.x;
    int v = (t < 98) ? bsum[t] : 0;
    s[t] = v;
    __syncthreads();
#pragma unroll
    for (int off = 1; off < 256; off <<= 1) {
        int tmp = (t >= off) ? s[t - off] : 0;
        __syncthreads();
        s[t] += tmp;
        __syncthreads();
    }
    if (t < 98) bsum[t] = s[t] - v;  // exclusive
    __syncthreads();
    int nb = t * 512;
    gcur256[t] = (nb < NN) ? (cur[nb] + bsum[nb >> 10]) : NE;
}

extern "C" __global__ void __launch_bounds__(1024)
k_scanC(int* __restrict__ cur, const int* __restrict__ bsum) {
    int idx = blockIdx.x * 1024 + threadIdx.x;
    if (idx < NN) cur[idx] += bsum[blockIdx.x];
}

// Bucket pass A: coarse binning; ecp stores nontemporal (write-once stream).
extern "C" __global__ void __launch_bounds__(256)
k_coarse(const int* __restrict__ colv, const int* __restrict__ rowv,
         int* __restrict__ gcur256, unsigned long long* __restrict__ ecp) {
    __shared__ int lh[256];
    __shared__ int sbase[256];
    int t = threadIdx.x;
    lh[t] = 0;
    __syncthreads();
    int e0 = blockIdx.x * 2048 + t * 8;
    int cls[8], rws[8];
    if (e0 + 7 < NE) {
        int4 a = *reinterpret_cast<const int4*>(colv + e0);
        int4 b = *reinterpret_cast<const int4*>(colv + e0 + 4);
        int4 ra = *reinterpret_cast<const int4*>(rowv + e0);
        int4 rb = *reinterpret_cast<const int4*>(rowv + e0 + 4);
        cls[0] = a.x; cls[1] = a.y; cls[2] = a.z; cls[3] = a.w;
        cls[4] = b.x; cls[5] = b.y; cls[6] = b.z; cls[7] = b.w;
        rws[0] = ra.x; rws[1] = ra.y; rws[2] = ra.z; rws[3] = ra.w;
        rws[4] = rb.x; rws[5] = rb.y; rws[6] = rb.z; rws[7] = rb.w;
    } else {
#pragma unroll
        for (int j = 0; j < 8; ++j) {
            cls[j] = (e0 + j < NE) ? colv[e0 + j] : 0;
            rws[j] = (e0 + j < NE) ? rowv[e0 + j] : 0;
        }
    }
    int d[8];
#pragma unroll
    for (int j = 0; j < 8; ++j) {
        if (e0 + j < NE) {
            cls[j] = min(max(cls[j], 0), NN - 1);
            rws[j] = min(max(rws[j], 0), NN - 1);
            d[j] = cls[j] >> 9;
            atomicAdd(&lh[d[j]], 1);
        } else {
            d[j] = -1;
        }
    }
    __syncthreads();
    int cnt = lh[t];
    if (cnt) sbase[t] = atomicAdd(&gcur256[t], cnt);
    __syncthreads();
    lh[t] = 0;
    __syncthreads();
#pragma unroll
    for (int j = 0; j < 8; ++j) {
        if (d[j] >= 0) {
            int r = atomicAdd(&lh[d[j]], 1);
            __builtin_nontemporal_store(pack_ec(rws[j], cls[j], e0 + j),
                                        &ecp[sbase[d[j]] + r]);
        }
    }
}

// Bucket pass B: fine placement; ecp loads nontemporal (read-once stream).
extern "C" __global__ void __launch_bounds__(256)
k_fine(const unsigned long long* __restrict__ ecp, int* __restrict__ cur,
       unsigned long long* __restrict__ ec) {
    int p = (blockIdx.x * 256 + threadIdx.x) * 2;
    if (p + 1 >= NE + 1) return;  // NE even: full pairs only
    unsigned long long v0 = __builtin_nontemporal_load(&ecp[p]);
    unsigned long long v1 = __builtin_nontemporal_load(&ecp[p + 1]);
    int cl0 = (int)((v0 >> 30) & 0x1FFFFULL);
    int cl1 = (int)((v1 >> 30) & 0x1FFFFULL);
    cl0 = min(cl0, NN - 1);
    cl1 = min(cl1, NN - 1);
    int p0 = atomicAdd(&cur[cl0], 1);
    int p1 = atomicAdd(&cur[cl1], 1);
    ec[p0] = v0;
    ec[p1] = v1;
}

// Single-pass bucket (fallback when ws too small for ecp/contrib).
extern "C" __global__ void __launch_bounds__(256)
k_bucket(const int* __restrict__ colv, const int* __restrict__ rowv,
         int* __restrict__ cur, unsigned long long* __restrict__ ec) {
    int e = blockIdx.x * 256 + threadIdx.x;
    if (e >= NE) return;
    int cl = colv[e];
    cl = min(max(cl, 0), NN - 1);
    int r = rowv[e];
    r = min(max(r, 0), NN - 1);
    int pos = atomicAdd(&cur[cl], 1);
    ec[pos] = pack_ec(r, cl, e);
}

// K2: FUSED agg + out_pre + h projection.
extern "C" __global__ void __launch_bounds__(256)
k_aggoh(const unsigned long long* __restrict__ ec, const int* __restrict__ cur,
        const unsigned short* __restrict__ ybf, unsigned short* xwr_h,
        const float* __restrict__ bl, const float* __restrict__ Wg,
        const float* __restrict__ bg, const float* __restrict__ hb,
        float* __restrict__ agg) {
    __shared__ float ol[4][64];
    int w = threadIdx.x >> 6, c = threadIdx.x & 63;
    int i = blockIdx.x * 4 + w;
    if (i >= NN) return;
    int start = (i == 0) ? 0 : cur[i - 1];
    int end = cur[i];
    float xwr = bf2f(xwr_h[(size_t)i * OC + c]);  // read before any write
    float acc = 0.0f;
    int p = start;
    for (; p + 7 < end; p += 8) {
        int r0 = (int)(ec[p + 0] >> 47);
        int r1 = (int)(ec[p + 1] >> 47);
        int r2 = (int)(ec[p + 2] >> 47);
        int r3 = (int)(ec[p + 3] >> 47);
        int r4 = (int)(ec[p + 4] >> 47);
        int r5 = (int)(ec[p + 5] >> 47);
        int r6 = (int)(ec[p + 6] >> 47);
        int r7 = (int)(ec[p + 7] >> 47);
        unsigned short u0 = ybf[(size_t)r0 * OC + c];
        unsigned short u1 = ybf[(size_t)r1 * OC + c];
        unsigned short u2 = ybf[(size_t)r2 * OC + c];
        unsigned short u3 = ybf[(size_t)r3 * OC + c];
        unsigned short u4 = ybf[(size_t)r4 * OC + c];
        unsigned short u5 = ybf[(size_t)r5 * OC + c];
        unsigned short u6 = ybf[(size_t)r6 * OC + c];
        unsigned short u7 = ybf[(size_t)r7 * OC + c];
        acc += bf2f(u0); acc += bf2f(u1); acc += bf2f(u2); acc += bf2f(u3);
        acc += bf2f(u4); acc += bf2f(u5); acc += bf2f(u6); acc += bf2f(u7);
    }
    for (; p < end; ++p) {
        int r0 = (int)(ec[p] >> 47);
        acc += bf2f(ybf[(size_t)r0 * OC + c]);
    }
    float inv = 1.0f / fmaxf((float)(end - start), 1.0f);
    float o = fmaf(acc, inv, bl[c] + xwr);
    agg[(size_t)i * OC + c] = o;
    ol[w][c] = o;
    __builtin_amdgcn_wave_barrier();
    float h0 = bg[c] + hb[c];
    float h1 = 0.0f, h2 = 0.0f, h3 = 0.0f;
#pragma unroll
    for (int k = 0; k < OC; k += 4) {
        float o0 = ol[w][k + 0], o1 = ol[w][k + 1];
        float o2 = ol[w][k + 2], o3 = ol[w][k + 3];
        h0 = fmaf(o0, Wg[(k + 0) * OC + c], h0);
        h1 = fmaf(o1, Wg[(k + 1) * OC + c], h1);
        h2 = fmaf(o2, Wg[(k + 2) * OC + c], h2);
        h3 = fmaf(o3, Wg[(k + 3) * OC + c], h3);
    }
    float h = (h0 + h1) + (h2 + h3);
    xwr_h[(size_t)i * OC + (c & 15) * 4 + (c >> 4)] = f2bf(h);
}

// K4-NS: MFMA gating, NO atomics. eattr loads + contrib stores nontemporal
// (write-once/read-once streams) so hswz/ybf stay L2-resident.
extern "C" __global__ void __launch_bounds__(256, 3)
k_gate_ns(const unsigned long long* __restrict__ ec, const float* __restrict__ eattr,
          const unsigned short* __restrict__ WfT, const unsigned short* __restrict__ WeT,
          const float* __restrict__ be, const unsigned short* __restrict__ hswz,
          unsigned short* __restrict__ contrib) {
    int lane = threadIdx.x & 63;
    int w = threadIdx.x >> 6;
    int tb = (blockIdx.x * 4 + w) * 64;

    unsigned long long ev = ec[tb + lane];
    int e = (int)(ev & 0x3FFFFFFFULL);
    int cl = (int)((ev >> 30) & 0x1FFFFULL);
    int c = lane & 15, g = lane >> 4;

    int erow0 = __shfl(e, 0 * 16 + c);
    int erow1 = __shfl(e, 1 * 16 + c);
    int erow2 = __shfl(e, 2 * 16 + c);
    int erow3 = __shfl(e, 3 * 16 + c);
    int clx[16];
#pragma unroll
    for (int mt = 0; mt < 4; ++mt)
#pragma unroll
        for (int r = 0; r < 4; ++r)
            clx[mt * 4 + r] = __shfl(cl, mt * 16 + g * 4 + r);

    uint2 hg[16];
#pragma unroll
    for (int q = 0; q < 16; ++q)
        hg[q] = *reinterpret_cast<const uint2*>(hswz + (size_t)clx[q] * OC + c * 4);

    bf16x8 bwf[4], bwe[4];
    float bev[4];
#pragma unroll
    for (int nt = 0; nt < 4; ++nt) {
        int ch = nt * 16 + c;
        bwf[nt] = *reinterpret_cast<const bf16x8*>(WfT + ch * ED + g * 8);
        bwe[nt] = *reinterpret_cast<const bf16x8*>(WeT + ch * ED + g * 8);
        bev[nt] = be[ch];
    }

    const f32x4* q0p = reinterpret_cast<const f32x4*>(eattr + (size_t)erow0 * ED + g * 8);
    const f32x4* q1p = reinterpret_cast<const f32x4*>(eattr + (size_t)erow1 * ED + g * 8);
    const f32x4* q2p = reinterpret_cast<const f32x4*>(eattr + (size_t)erow2 * ED + g * 8);
    const f32x4* q3p = reinterpret_cast<const f32x4*>(eattr + (size_t)erow3 * ED + g * 8);
    f32x4 alo0 = __builtin_nontemporal_load(q0p);
    f32x4 ahi0 = __builtin_nontemporal_load(q0p + 1);
    f32x4 alo1 = __builtin_nontemporal_load(q1p);
    f32x4 ahi1 = __builtin_nontemporal_load(q1p + 1);
    f32x4 alo2 = __builtin_nontemporal_load(q2p);
    f32x4 ahi2 = __builtin_nontemporal_load(q2p + 1);
    f32x4 alo3 = __builtin_nontemporal_load(q3p);
    f32x4 ahi3 = __builtin_nontemporal_load(q3p + 1);

    bf16x8 afr[4];
    {
        union { bf16x8 v; unsigned d[4]; } pk;
#define PACKA(idx, lo, hi)                         \
        pk.d[0] = cvtpk(lo.x, lo.y);               \
        pk.d[1] = cvtpk(lo.z, lo.w);               \
        pk.d[2] = cvtpk(hi.x, hi.y);               \
        pk.d[3] = cvtpk(hi.z, hi.w);               \
        afr[idx] = pk.v;
        PACKA(0, alo0, ahi0)
        PACKA(1, alo1, ahi1)
        PACKA(2, alo2, ahi2)
        PACKA(3, alo3, ahi3)
#undef PACKA
    }

#pragma unroll
    for (int mt = 0; mt < 4; ++mt) {
        uint2 h0 = hg[mt * 4 + 0];
        uint2 h1 = hg[mt * 4 + 1];
        uint2 h2 = hg[mt * 4 + 2];
        uint2 h3 = hg[mt * 4 + 3];
        float sv[4][4];
#pragma unroll
        for (int nt = 0; nt < 4; ++nt) {
            f32x4 cz, ce;
            unsigned w0 = (nt < 2) ? h0.x : h0.y;
            unsigned w1 = (nt < 2) ? h1.x : h1.y;
            unsigned w2 = (nt < 2) ? h2.x : h2.y;
            unsigned w3 = (nt < 2) ? h3.x : h3.y;
            cz[0] = bf2f((unsigned short)((nt & 1) ? (w0 >> 16) : (w0 & 0xffffu)));
            cz[1] = bf2f((unsigned short)((nt & 1) ? (w1 >> 16) : (w1 & 0xffffu)));
            cz[2] = bf2f((unsigned short)((nt & 1) ? (w2 >> 16) : (w2 & 0xffffu)));
            cz[3] = bf2f((unsigned short)((nt & 1) ? (w3 >> 16) : (w3 & 0xffffu)));
            ce[0] = bev[nt]; ce[1] = bev[nt]; ce[2] = bev[nt]; ce[3] = bev[nt];
            f32x4 z  = __builtin_amdgcn_mfma_f32_16x16x32_bf16(afr[mt], bwf[nt], cz, 0, 0, 0);
            f32x4 ea = __builtin_amdgcn_mfma_f32_16x16x32_bf16(afr[mt], bwe[nt], ce, 0, 0, 0);
            sv[nt][0] = sigmoidf_(z[0]) * ea[0];
            sv[nt][1] = sigmoidf_(z[1]) * ea[1];
            sv[nt][2] = sigmoidf_(z[2]) * ea[2];
            sv[nt][3] = sigmoidf_(z[3]) * ea[3];
        }
#pragma unroll
        for (int r = 0; r < 4; ++r) {
            int row = tb + mt * 16 + g * 4 + r;
            unsigned long long pk64 =
                (unsigned long long)cvtpk(sv[0][r], sv[1][r]) |
                ((unsigned long long)cvtpk(sv[2][r], sv[3][r]) << 32);
            __builtin_nontemporal_store(pk64,
                reinterpret_cast<unsigned long long*>(
                    contrib + (size_t)row * OC + c * 4));
        }
    }
}

// K4-AT: atomic fallback.
extern "C" __global__ void __launch_bounds__(256, 3)
k_gate_at(const unsigned long long* __restrict__ ec, const float* __restrict__ eattr,
          const unsigned short* __restrict__ WfT, const unsigned short* __restrict__ WeT,
          const float* __restrict__ be, const unsigned short* __restrict__ hswz,
          float* __restrict__ agg) {
    int lane = threadIdx.x & 63;
    int w = threadIdx.x >> 6;
    int tb = (blockIdx.x * 4 + w) * 64;

    unsigned long long ev = ec[tb + lane];
    int e = (int)(ev & 0x3FFFFFFFULL);
    int cl = (int)((ev >> 30) & 0x1FFFFULL);
    int c = lane & 15, g = lane >> 4;

    int erow0 = __shfl(e, 0 * 16 + c);
    int erow1 = __shfl(e, 1 * 16 + c);
    int erow2 = __shfl(e, 2 * 16 + c);
    int erow3 = __shfl(e, 3 * 16 + c);
    int clx[16];
#pragma unroll
    for (int mt = 0; mt < 4; ++mt)
#pragma unroll
        for (int r = 0; r < 4; ++r)
            clx[mt * 4 + r] = __shfl(cl, mt * 16 + g * 4 + r);

    uint2 hg[16];
#pragma unroll
    for (int q = 0; q < 16; ++q)
        hg[q] = *reinterpret_cast<const uint2*>(hswz + (size_t)clx[q] * OC + c * 4);

    bf16x8 bwf[4], bwe[4];
    float bev[4];
#pragma unroll
    for (int nt = 0; nt < 4; ++nt) {
        int ch = nt * 16 + c;
        bwf[nt] = *reinterpret_cast<const bf16x8*>(WfT + ch * ED + g * 8);
        bwe[nt] = *reinterpret_cast<const bf16x8*>(WeT + ch * ED + g * 8);
        bev[nt] = be[ch];
    }

    float4 alo0 = reinterpret_cast<const float4*>(eattr + (size_t)erow0 * ED + g * 8)[0];
    float4 ahi0 = reinterpret_cast<const float4*>(eattr + (size_t)erow0 * ED + g * 8)[1];
    float4 alo1 = reinterpret_cast<const float4*>(eattr + (size_t)erow1 * ED + g * 8)[0];
    float4 ahi1 = reinterpret_cast<const float4*>(eattr + (size_t)erow1 * ED + g * 8)[1];
    float4 alo2 = reinterpret_cast<const float4*>(eattr + (size_t)erow2 * ED + g * 8)[0];
    float4 ahi2 = reinterpret_cast<const float4*>(eattr + (size_t)erow2 * ED + g * 8)[1];
    float4 alo3 = reinterpret_cast<const float4*>(eattr + (size_t)erow3 * ED + g * 8)[0];
    float4 ahi3 = reinterpret_cast<const float4*>(eattr + (size_t)erow3 * ED + g * 8)[1];

    bf16x8 afr[4];
    {
        union { bf16x8 v; unsigned d[4]; } pk;
#define PACKA(idx, lo, hi)                         \
        pk.d[0] = cvtpk(lo.x, lo.y);               \
        pk.d[1] = cvtpk(lo.z, lo.w);               \
        pk.d[2] = cvtpk(hi.x, hi.y);               \
        pk.d[3] = cvtpk(hi.z, hi.w);               \
        afr[idx] = pk.v;
        PACKA(0, alo0, ahi0)
        PACKA(1, alo1, ahi1)
        PACKA(2, alo2, ahi2)
        PACKA(3, alo3, ahi3)
#undef PACKA
    }

#pragma unroll
    for (int mt = 0; mt < 4; ++mt) {
        int cl0 = clx[mt * 4 + 0];
        int cl1 = clx[mt * 4 + 1];
        int cl2 = clx[mt * 4 + 2];
        int cl3 = clx[mt * 4 + 3];
        uint2 h0 = hg[mt * 4 + 0];
        uint2 h1 = hg[mt * 4 + 1];
        uint2 h2 = hg[mt * 4 + 2];
        uint2 h3 = hg[mt * 4 + 3];
#pragma unroll
        for (int nt = 0; nt < 4; ++nt) {
            int ch = nt * 16 + c;
            f32x4 cz, ce;
            unsigned w0 = (nt < 2) ? h0.x : h0.y;
            unsigned w1 = (nt < 2) ? h1.x : h1.y;
            unsigned w2 = (nt < 2) ? h2.x : h2.y;
            unsigned w3 = (nt < 2) ? h3.x : h3.y;
            cz[0] = bf2f((unsigned short)((nt & 1) ? (w0 >> 16) : (w0 & 0xffffu)));
            cz[1] = bf2f((unsigned short)((nt & 1) ? (w1 >> 16) : (w1 & 0xffffu)));
            cz[2] = bf2f((unsigned short)((nt & 1) ? (w2 >> 16) : (w2 & 0xffffu)));
            cz[3] = bf2f((unsigned short)((nt & 1) ? (w3 >> 16) : (w3 & 0xffffu)));
            ce[0] = bev[nt]; ce[1] = bev[nt]; ce[2] = bev[nt]; ce[3] = bev[nt];
            f32x4 z  = __builtin_amdgcn_mfma_f32_16x16x32_bf16(afr[mt], bwf[nt], cz, 0, 0, 0);
            f32x4 ea = __builtin_amdgcn_mfma_f32_16x16x32_bf16(afr[mt], bwe[nt], ce, 0, 0, 0);
            float c0 = sigmoidf_(z[0]) * ea[0];
            float c1 = sigmoidf_(z[1]) * ea[1];
            float c2 = sigmoidf_(z[2]) * ea[2];
            float c3 = sigmoidf_(z[3]) * ea[3];
            float s = c0;
            int t = cl0;
            if (cl1 != t) { atomicAdd(&agg[(size_t)t * OC + ch], s); s = 0.0f; t = cl1; }
            s += c1;
            if (cl2 != t) { atomicAdd(&agg[(size_t)t * OC + ch], s); s = 0.0f; t = cl2; }
            s += c2;
            if (cl3 != t) { atomicAdd(&agg[(size_t)t * OC + ch], s); s = 0.0f; t = cl3; }
            s += c3;
            atomicAdd(&agg[(size_t)t * OC + ch], s);
        }
    }
}

// K4b (NS): segmented sum of contrib + fused BN stats; contrib loads nt.
extern "C" __global__ void __launch_bounds__(256)
k_csumst(const unsigned short* __restrict__ contrib, const int* __restrict__ cur,
         float* __restrict__ agg, float* __restrict__ stats) {
    __shared__ float ls[256], lq[256];
    int w = threadIdx.x >> 6, c = threadIdx.x & 63;
    int ch = (c >> 2) + 16 * (c & 3);
    float sv = 0.0f, sq = 0.0f;
    for (int i = blockIdx.x * 4 + w; i < NN; i += 2048 * 4) {
        int start = (i == 0) ? 0 : cur[i - 1];
        int end = cur[i];
        float s = 0.0f;
        int p = start;
        for (; p + 7 < end; p += 8) {
            unsigned short u0 = __builtin_nontemporal_load(contrib + (size_t)(p + 0) * OC + c);
            unsigned short u1 = __builtin_nontemporal_load(contrib + (size_t)(p + 1) * OC + c);
            unsigned short u2 = __builtin_nontemporal_load(contrib + (size_t)(p + 2) * OC + c);
            unsigned short u3 = __builtin_nontemporal_load(contrib + (size_t)(p + 3) * OC + c);
            unsigned short u4 = __builtin_nontemporal_load(contrib + (size_t)(p + 4) * OC + c);
            unsigned short u5 = __builtin_nontemporal_load(contrib + (size_t)(p + 5) * OC + c);
            unsigned short u6 = __builtin_nontemporal_load(contrib + (size_t)(p + 6) * OC + c);
            unsigned short u7 = __builtin_nontemporal_load(contrib + (size_t)(p + 7) * OC + c);
            s += bf2f(u0); s += bf2f(u1); s += bf2f(u2); s += bf2f(u3);
            s += bf2f(u4); s += bf2f(u5); s += bf2f(u6); s += bf2f(u7);
        }
        for (; p < end; ++p)
            s += bf2f(__builtin_nontemporal_load(contrib + (size_t)p * OC + c));
        float v = agg[(size_t)i * OC + ch] + s;
        agg[(size_t)i * OC + ch] = v;
        sv += v;
        sq = fmaf(v, v, sq);
    }
    ls[threadIdx.x] = sv;
    lq[threadIdx.x] = sq;
    __syncthreads();
    if (threadIdx.x < 64) {
        float a = ls[c] + ls[c + 64] + ls[c + 128] + ls[c + 192];
        float b = lq[c] + lq[c + 64] + lq[c + 128] + lq[c + 192];
        atomicAdd(&stats[ch], a);
        atomicAdd(&stats[OC + ch], b);
    }
}

// K5: BN batch stats (AT path only).
extern "C" __global__ void __launch_bounds__(256)
k_stats(const float* __restrict__ a, float* __restrict__ stats) {
    __shared__ float ls[256], lq[256];
    int t = threadIdx.x;
    float s = 0.0f, q = 0.0f;
    for (size_t idx = (size_t)blockIdx.x * 256 + t; idx < (size_t)NN * OC;
         idx += (size_t)gridDim.x * 256) {
        float v = a[idx];
        s += v;
        q = fmaf(v, v, q);
    }
    ls[t] = s; lq[t] = q;
    __syncthreads();
    if (t < OC) {
        s = ls[t] + ls[t + 64] + ls[t + 128] + ls[t + 192];
        q = lq[t] + lq[t + 64] + lq[t + 128] + lq[t + 192];
        atomicAdd(&stats[t], s);
        atomicAdd(&stats[OC + t], q);
    }
}

// K6: BN normalize + residual(2x) + ReLU. agg dead after, out never re-read:
// both nontemporal.
extern "C" __global__ void __launch_bounds__(256)
k_final(const float* __restrict__ a, const float* __restrict__ stats,
        const float* __restrict__ gamma, const float* __restrict__ beta,
        float* __restrict__ out) {
    size_t idx = (size_t)blockIdx.x * 256 + threadIdx.x;
    if (idx >= (size_t)NN * OC) return;
    int c = (int)(idx & 63);
    float mu = stats[c] * (1.0f / NN);
    float var = stats[OC + c] * (1.0f / NN) - mu * mu;
    float v = __builtin_nontemporal_load(a + idx);
    float y = fmaf(gamma[c] * (v - mu), rsqrtf(var + 1e-5f), beta[c]);
    __builtin_nontemporal_store(fmaxf(2.0f * y, 0.0f), out + idx);
}

extern "C" void kernel_launch(void* const* d_in, const int* in_sizes, int n_in,
                              void* d_out, int out_size, void* d_ws, size_t ws_size,
                              hipStream_t stream) {
    const float* x     = (const float*)d_in[0];
    const int*   ei    = (const int*)d_in[1];   // (2, NE) int32
    const float* eattr = (const float*)d_in[2];
    const float* Wl    = (const float*)d_in[3];
    const float* bl    = (const float*)d_in[4];
    const float* Wr    = (const float*)d_in[5];
    const float* We    = (const float*)d_in[6];
    const float* be    = (const float*)d_in[7];
    const float* Wg    = (const float*)d_in[8];
    const float* bg    = (const float*)d_in[9];
    const float* gamma = (const float*)d_in[10];
    const float* beta  = (const float*)d_in[11];
    float* out = (float*)d_out;

    float* agg = (float*)d_ws;
    unsigned short* ybf   = (unsigned short*)(agg + (size_t)NN * OC);
    unsigned short* xwrbf = ybf + (size_t)NN * OC;   // becomes hswz after k_aggoh
    unsigned long long* ec = (unsigned long long*)(xwrbf + (size_t)NN * OC);
    int* cur   = (int*)(ec + (size_t)NE);
    int* bsum  = cur + NN;
    float* stats = (float*)(bsum + 128);
    unsigned short* WfT  = (unsigned short*)(stats + 128);
    unsigned short* WeT  = WfT + ED * OC;
    unsigned short* WlrT = WeT + ED * OC;
    float* hb = (float*)(WlrT + 2 * INC * OC);
    int* gcur256 = (int*)(hb + OC);
    unsigned short* contrib = (unsigned short*)(gcur256 + 256);
    unsigned long long* ecp =
        (unsigned long long*)(((size_t)contrib + 7) & ~(size_t)7);
    unsigned short* hswz = xwrbf;

    size_t base_bytes = (size_t)((char*)contrib - (char*)d_ws);
    bool ns = ws_size >= base_bytes + 8 + (size_t)NE * OC * sizeof(unsigned short);

    const int* rowv = ei;
    const int* colv = ei + NE;

    hipMemsetAsync(cur, 0, NN * sizeof(int), stream);
    hipMemsetAsync(stats, 0, 2 * OC * sizeof(float), stream);

    k_wfuse<<<(2 * ED * OC + OC + 2 * INC * OC + 255) / 256, 256, 0, stream>>>(
        We, be, Wg, Wl, Wr, WfT, WeT, hb, WlrT);
    k_xw<<<(NN + 63) / 64, 256, 0, stream>>>(x, WlrT, ybf, xwrbf, colv, cur);
    k_scanA<<<98, 1024, 0, stream>>>(cur, cur, bsum);
    k_scanB<<<1, 256, 0, stream>>>(bsum, cur, gcur256);
    k_scanC<<<98, 1024, 0, stream>>>(cur, bsum);
    if (ns) {
        k_coarse<<<(NE + 2047) / 2048, 256, 0, stream>>>(colv, rowv, gcur256, ecp);
        k_fine<<<(NE / 2 + 255) / 256, 256, 0, stream>>>(ecp, cur, ec);
    } else {
        k_bucket<<<(NE + 255) / 256, 256, 0, stream>>>(colv, rowv, cur, ec);
    }
    k_aggoh<<<(NN + 3) / 4, 256, 0, stream>>>(ec, cur, ybf, xwrbf, bl, Wg, bg, hb, agg);
    if (ns) {
        k_gate_ns<<<NE / 256, 256, 0, stream>>>(ec, eattr, WfT, WeT, be, hswz, contrib);
        k_csumst<<<2048, 256, 0, stream>>>(contrib, cur, agg, stats);
    } else {
        k_gate_at<<<NE / 256, 256, 0, stream>>>(ec, eattr, WfT, WeT, be, hswz, agg);
        k_stats<<<2048, 256, 0, stream>>>(agg, stats);
    }
    k_final<<<((size_t)NN * OC + 255) / 256, 256, 0, stream>>>(agg, stats, gamma, beta, out);
}

// Round 17
// 471.799 us; speedup vs baseline: 1.0552x; 1.0552x over previous
//
#include <hip/hip_runtime.h>
#include <math.h>

#define NN 100000
#define NE 1600000
#define INC 128
#define OC 64
#define ED 32

typedef __attribute__((ext_vector_type(8))) short bf16x8;
typedef __attribute__((ext_vector_type(4))) float f32x4;

__device__ __forceinline__ float sigmoidf_(float z) {
    return __builtin_amdgcn_rcpf(1.0f + __expf(-z));
}

__device__ __forceinline__ unsigned short f2bf(float x) {
    unsigned int u = __float_as_uint(x);
    unsigned int r = u + 0x7FFFu + ((u >> 16) & 1u);
    return (unsigned short)(r >> 16);
}
__device__ __forceinline__ float bf2f(unsigned short u) {
    return __uint_as_float((unsigned int)u << 16);
}
__device__ __forceinline__ unsigned cvtpk(float lo, float hi) {
    unsigned r;
    asm("v_cvt_pk_bf16_f32 %0, %1, %2" : "=v"(r) : "v"(lo), "v"(hi));
    return r;
}

__device__ __forceinline__ unsigned long long pack_ec(int r, int cl, int e) {
    return ((unsigned long long)(unsigned)r << 47) |
           ((unsigned long long)(unsigned)cl << 30) | (unsigned)e;
}

// K0: weight prep.
extern "C" __global__ void __launch_bounds__(256)
k_wfuse(const float* __restrict__ We, const float* __restrict__ be,
        const float* __restrict__ Wg, const float* __restrict__ Wl,
        const float* __restrict__ Wr, unsigned short* __restrict__ WfT,
        unsigned short* __restrict__ WeT, float* __restrict__ hb,
        unsigned short* __restrict__ WlrT) {
    int idx = blockIdx.x * 256 + threadIdx.x;
    if (idx < ED * OC) {
        int ch = idx >> 5, d = idx & 31;
        float acc = 0.0f;
#pragma unroll
        for (int k = 0; k < OC; ++k)
            acc = fmaf(We[d * OC + k], Wg[(OC + k) * OC + ch], acc);
        WfT[idx] = f2bf(acc);
    } else if (idx < 2 * ED * OC) {
        int i2 = idx - ED * OC;
        int ch = i2 >> 5, d = i2 & 31;
        WeT[i2] = f2bf(We[d * OC + ch]);
    } else if (idx < 2 * ED * OC + OC) {
        int j = idx - 2 * ED * OC;
        float acc = 0.0f;
#pragma unroll
        for (int k = 0; k < OC; ++k)
            acc = fmaf(be[k], Wg[(OC + k) * OC + j], acc);
        hb[j] = acc;
    } else if (idx < 2 * ED * OC + OC + 2 * INC * OC) {
        int i3 = idx - (2 * ED * OC + OC);
        int ch = i3 >> 7, k = i3 & 127;
        float v = (ch < OC) ? Wl[k * OC + ch] : Wr[k * OC + (ch - OC)];
        WlrT[i3] = f2bf(v);
    }
}

// K1: MFMA GEMM [yl | xwr](bf16) = x @ [Wl | Wr], hist fused (fire-and-forget).
extern "C" __global__ void __launch_bounds__(256)
k_xw(const float* __restrict__ x, const unsigned short* __restrict__ WlrT,
     unsigned short* __restrict__ ybf, unsigned short* __restrict__ xwrbf,
     const int* __restrict__ colv, int* __restrict__ cnti) {
    int t = threadIdx.x;
    {
        int eb = (blockIdx.x * 256 + t) * 4;
        if (eb + 3 < NE) {
            int4 cv = *reinterpret_cast<const int4*>(colv + eb);
            int c0 = min(max(cv.x, 0), NN - 1);
            int c1 = min(max(cv.y, 0), NN - 1);
            int c2 = min(max(cv.z, 0), NN - 1);
            int c3 = min(max(cv.w, 0), NN - 1);
            atomicAdd(&cnti[c0], 1);
            atomicAdd(&cnti[c1], 1);
            atomicAdd(&cnti[c2], 1);
            atomicAdd(&cnti[c3], 1);
        }
    }

    __shared__ unsigned short xs[64][136];
    int base = blockIdx.x * 64;
    {
        int rr = t >> 2, cc = (t & 3) * 32;
        int grow = base + rr;
        if (grow < NN) {
            const float4* xp = reinterpret_cast<const float4*>(
                x + (size_t)grow * INC + cc);
#pragma unroll
            for (int q = 0; q < 8; ++q) {
                float4 v = xp[q];
                uint2 uv;
                uv.x = cvtpk(v.x, v.y);
                uv.y = cvtpk(v.z, v.w);
                *reinterpret_cast<uint2*>(&xs[rr][cc + q * 4]) = uv;
            }
        } else {
#pragma unroll
            for (int q = 0; q < 8; ++q) {
                uint2 uv; uv.x = 0u; uv.y = 0u;
                *reinterpret_cast<uint2*>(&xs[rr][cc + q * 4]) = uv;
            }
        }
    }
    __syncthreads();

    int lane = t & 63, w = t >> 6;
    int c = lane & 15, g = lane >> 4;

    bf16x8 bw0[4], bw1[4];
#pragma unroll
    for (int kk = 0; kk < 4; ++kk) {
        bw0[kk] = *reinterpret_cast<const bf16x8*>(
            WlrT + (w * 32 + 0 * 16 + c) * INC + kk * 32 + g * 8);
        bw1[kk] = *reinterpret_cast<const bf16x8*>(
            WlrT + (w * 32 + 1 * 16 + c) * INC + kk * 32 + g * 8);
    }

    f32x4 acc[4][2];
#pragma unroll
    for (int mt = 0; mt < 4; ++mt)
#pragma unroll
        for (int nt = 0; nt < 2; ++nt)
            acc[mt][nt] = (f32x4){0.0f, 0.0f, 0.0f, 0.0f};

#pragma unroll
    for (int kk = 0; kk < 4; ++kk) {
        bf16x8 a0 = *reinterpret_cast<const bf16x8*>(&xs[0 * 16 + c][kk * 32 + g * 8]);
        bf16x8 a1 = *reinterpret_cast<const bf16x8*>(&xs[1 * 16 + c][kk * 32 + g * 8]);
        bf16x8 a2 = *reinterpret_cast<const bf16x8*>(&xs[2 * 16 + c][kk * 32 + g * 8]);
        bf16x8 a3 = *reinterpret_cast<const bf16x8*>(&xs[3 * 16 + c][kk * 32 + g * 8]);
        acc[0][0] = __builtin_amdgcn_mfma_f32_16x16x32_bf16(a0, bw0[kk], acc[0][0], 0, 0, 0);
        acc[0][1] = __builtin_amdgcn_mfma_f32_16x16x32_bf16(a0, bw1[kk], acc[0][1], 0, 0, 0);
        acc[1][0] = __builtin_amdgcn_mfma_f32_16x16x32_bf16(a1, bw0[kk], acc[1][0], 0, 0, 0);
        acc[1][1] = __builtin_amdgcn_mfma_f32_16x16x32_bf16(a1, bw1[kk], acc[1][1], 0, 0, 0);
        acc[2][0] = __builtin_amdgcn_mfma_f32_16x16x32_bf16(a2, bw0[kk], acc[2][0], 0, 0, 0);
        acc[2][1] = __builtin_amdgcn_mfma_f32_16x16x32_bf16(a2, bw1[kk], acc[2][1], 0, 0, 0);
        acc[3][0] = __builtin_amdgcn_mfma_f32_16x16x32_bf16(a3, bw0[kk], acc[3][0], 0, 0, 0);
        acc[3][1] = __builtin_amdgcn_mfma_f32_16x16x32_bf16(a3, bw1[kk], acc[3][1], 0, 0, 0);
    }

#pragma unroll
    for (int mt = 0; mt < 4; ++mt) {
#pragma unroll
        for (int nt = 0; nt < 2; ++nt) {
            int ch = w * 32 + nt * 16 + c;
#pragma unroll
            for (int j = 0; j < 4; ++j) {
                int row = base + mt * 16 + g * 4 + j;
                if (row < NN) {
                    unsigned short vb = f2bf(acc[mt][nt][j]);
                    if (ch < OC) ybf[(size_t)row * OC + ch] = vb;
                    else         xwrbf[(size_t)row * OC + (ch - OC)] = vb;
                }
            }
        }
    }
}

extern "C" __global__ void __launch_bounds__(1024)
k_scanA(const int* __restrict__ cnti, int* __restrict__ cur,
        int* __restrict__ bsum) {
    __shared__ int s[1024];
    int t = threadIdx.x;
    int idx = blockIdx.x * 1024 + t;
    int v = (idx < NN) ? cnti[idx] : 0;
    s[t] = v;
    __syncthreads();
#pragma unroll
    for (int off = 1; off < 1024; off <<= 1) {
        int tmp = (t >= off) ? s[t - off] : 0;
        __syncthreads();
        s[t] += tmp;
        __syncthreads();
    }
    if (idx < NN) cur[idx] = s[t] - v;
    if (t == 1023) bsum[blockIdx.x] = s[1023];
}

extern "C" __global__ void __launch_bounds__(128)
k_scanB(int* __restrict__ bsum) {
    __shared__ int s[128];
    int t = threadIdx.x;
    int v = (t < 98) ? bsum[t] : 0;
    s[t] = v;
    __syncthreads();
#pragma unroll
    for (int off = 1; off < 128; off <<= 1) {
        int tmp = (t >= off) ? s[t - off] : 0;
        __syncthreads();
        s[t] += tmp;
        __syncthreads();
    }
    if (t < 98) bsum[t] = s[t] - v;
}

extern "C" __global__ void __launch_bounds__(1024)
k_scanC(int* __restrict__ cur, const int* __restrict__ bsum) {
    int idx = blockIdx.x * 1024 + threadIdx.x;
    if (idx < NN) cur[idx] += bsum[blockIdx.x];
}

// coarse-bucket cursors: gcur256[t] = START of coarse bucket t = cur[t*512].
extern "C" __global__ void __launch_bounds__(256)
k_init256(const int* __restrict__ cur, int* __restrict__ gcur256) {
    int t = threadIdx.x;
    int nb = t * 512;
    gcur256[t] = (nb < NN) ? cur[nb] : NE;
}

// Bucket pass A: bin 2048 edges/block by coarse digit cl>>9 via LDS ranks;
// per-digit global reservation -> contiguous 8B entries per digit per block.
extern "C" __global__ void __launch_bounds__(256)
k_coarse(const int* __restrict__ colv, const int* __restrict__ rowv,
         int* __restrict__ gcur256, unsigned long long* __restrict__ ecp) {
    __shared__ int lh[256];
    __shared__ int sbase[256];
    int t = threadIdx.x;
    lh[t] = 0;
    __syncthreads();
    int e0 = blockIdx.x * 2048 + t * 8;
    int cls[8], rws[8];
    if (e0 + 7 < NE) {
        int4 a = *reinterpret_cast<const int4*>(colv + e0);
        int4 b = *reinterpret_cast<const int4*>(colv + e0 + 4);
        int4 ra = *reinterpret_cast<const int4*>(rowv + e0);
        int4 rb = *reinterpret_cast<const int4*>(rowv + e0 + 4);
        cls[0] = a.x; cls[1] = a.y; cls[2] = a.z; cls[3] = a.w;
        cls[4] = b.x; cls[5] = b.y; cls[6] = b.z; cls[7] = b.w;
        rws[0] = ra.x; rws[1] = ra.y; rws[2] = ra.z; rws[3] = ra.w;
        rws[4] = rb.x; rws[5] = rb.y; rws[6] = rb.z; rws[7] = rb.w;
    } else {
#pragma unroll
        for (int j = 0; j < 8; ++j) {
            cls[j] = (e0 + j < NE) ? colv[e0 + j] : 0;
            rws[j] = (e0 + j < NE) ? rowv[e0 + j] : 0;
        }
    }
    int d[8];
#pragma unroll
    for (int j = 0; j < 8; ++j) {
        if (e0 + j < NE) {
            cls[j] = min(max(cls[j], 0), NN - 1);
            rws[j] = min(max(rws[j], 0), NN - 1);
            d[j] = cls[j] >> 9;
            atomicAdd(&lh[d[j]], 1);
        } else {
            d[j] = -1;
        }
    }
    __syncthreads();
    int cnt = lh[t];
    if (cnt) sbase[t] = atomicAdd(&gcur256[t], cnt);
    __syncthreads();
    lh[t] = 0;
    __syncthreads();
#pragma unroll
    for (int j = 0; j < 8; ++j) {
        if (d[j] >= 0) {
            int r = atomicAdd(&lh[d[j]], 1);
            ecp[sbase[d[j]] + r] = pack_ec(rws[j], cls[j], e0 + j);
        }
    }
}

// Bucket pass B: fine placement within L2-resident coarse regions.
extern "C" __global__ void __launch_bounds__(256)
k_fine(const unsigned long long* __restrict__ ecp, int* __restrict__ cur,
       unsigned long long* __restrict__ ec) {
    int p = blockIdx.x * 256 + threadIdx.x;
    if (p >= NE) return;
    unsigned long long v = ecp[p];
    int cl = (int)((v >> 30) & 0x1FFFFULL);
    cl = min(cl, NN - 1);  // defensive
    int pos = atomicAdd(&cur[cl], 1);
    ec[pos] = v;
}

// Single-pass bucket (fallback when ws too small for ecp/contrib).
extern "C" __global__ void __launch_bounds__(256)
k_bucket(const int* __restrict__ colv, const int* __restrict__ rowv,
         int* __restrict__ cur, unsigned long long* __restrict__ ec) {
    int e = blockIdx.x * 256 + threadIdx.x;
    if (e >= NE) return;
    int cl = colv[e];
    cl = min(max(cl, 0), NN - 1);
    int r = rowv[e];
    r = min(max(r, 0), NN - 1);
    int pos = atomicAdd(&cur[cl], 1);
    ec[pos] = pack_ec(r, cl, e);
}

// K2: FUSED agg + out_pre + h projection.
extern "C" __global__ void __launch_bounds__(256)
k_aggoh(const unsigned long long* __restrict__ ec, const int* __restrict__ cur,
        const unsigned short* __restrict__ ybf, unsigned short* xwr_h,
        const float* __restrict__ bl, const float* __restrict__ Wg,
        const float* __restrict__ bg, const float* __restrict__ hb,
        float* __restrict__ agg) {
    __shared__ float ol[4][64];
    int w = threadIdx.x >> 6, c = threadIdx.x & 63;
    int i = blockIdx.x * 4 + w;
    if (i >= NN) return;
    int start = (i == 0) ? 0 : cur[i - 1];
    int end = cur[i];
    float xwr = bf2f(xwr_h[(size_t)i * OC + c]);  // read before any write
    float acc = 0.0f;
    int p = start;
    for (; p + 7 < end; p += 8) {
        int r0 = (int)(ec[p + 0] >> 47);
        int r1 = (int)(ec[p + 1] >> 47);
        int r2 = (int)(ec[p + 2] >> 47);
        int r3 = (int)(ec[p + 3] >> 47);
        int r4 = (int)(ec[p + 4] >> 47);
        int r5 = (int)(ec[p + 5] >> 47);
        int r6 = (int)(ec[p + 6] >> 47);
        int r7 = (int)(ec[p + 7] >> 47);
        unsigned short u0 = ybf[(size_t)r0 * OC + c];
        unsigned short u1 = ybf[(size_t)r1 * OC + c];
        unsigned short u2 = ybf[(size_t)r2 * OC + c];
        unsigned short u3 = ybf[(size_t)r3 * OC + c];
        unsigned short u4 = ybf[(size_t)r4 * OC + c];
        unsigned short u5 = ybf[(size_t)r5 * OC + c];
        unsigned short u6 = ybf[(size_t)r6 * OC + c];
        unsigned short u7 = ybf[(size_t)r7 * OC + c];
        acc += bf2f(u0); acc += bf2f(u1); acc += bf2f(u2); acc += bf2f(u3);
        acc += bf2f(u4); acc += bf2f(u5); acc += bf2f(u6); acc += bf2f(u7);
    }
    for (; p < end; ++p) {
        int r0 = (int)(ec[p] >> 47);
        acc += bf2f(ybf[(size_t)r0 * OC + c]);
    }
    float inv = 1.0f / fmaxf((float)(end - start), 1.0f);
    float o = fmaf(acc, inv, bl[c] + xwr);
    agg[(size_t)i * OC + c] = o;
    ol[w][c] = o;
    __builtin_amdgcn_wave_barrier();
    float h0 = bg[c] + hb[c];
    float h1 = 0.0f, h2 = 0.0f, h3 = 0.0f;
#pragma unroll
    for (int k = 0; k < OC; k += 4) {
        float o0 = ol[w][k + 0], o1 = ol[w][k + 1];
        float o2 = ol[w][k + 2], o3 = ol[w][k + 3];
        h0 = fmaf(o0, Wg[(k + 0) * OC + c], h0);
        h1 = fmaf(o1, Wg[(k + 1) * OC + c], h1);
        h2 = fmaf(o2, Wg[(k + 2) * OC + c], h2);
        h3 = fmaf(o3, Wg[(k + 3) * OC + c], h3);
    }
    float h = (h0 + h1) + (h2 + h3);
    xwr_h[(size_t)i * OC + (c & 15) * 4 + (c >> 4)] = f2bf(h);
}

// K4-NS: MFMA gating, NO atomics.
extern "C" __global__ void __launch_bounds__(256, 3)
k_gate_ns(const unsigned long long* __restrict__ ec, const float* __restrict__ eattr,
          const unsigned short* __restrict__ WfT, const unsigned short* __restrict__ WeT,
          const float* __restrict__ be, const unsigned short* __restrict__ hswz,
          unsigned short* __restrict__ contrib) {
    int lane = threadIdx.x & 63;
    int w = threadIdx.x >> 6;
    int tb = (blockIdx.x * 4 + w) * 64;

    unsigned long long ev = ec[tb + lane];
    int e = (int)(ev & 0x3FFFFFFFULL);
    int cl = (int)((ev >> 30) & 0x1FFFFULL);
    int c = lane & 15, g = lane >> 4;

    int erow0 = __shfl(e, 0 * 16 + c);
    int erow1 = __shfl(e, 1 * 16 + c);
    int erow2 = __shfl(e, 2 * 16 + c);
    int erow3 = __shfl(e, 3 * 16 + c);
    int clx[16];
#pragma unroll
    for (int mt = 0; mt < 4; ++mt)
#pragma unroll
        for (int r = 0; r < 4; ++r)
            clx[mt * 4 + r] = __shfl(cl, mt * 16 + g * 4 + r);

    uint2 hg[16];
#pragma unroll
    for (int q = 0; q < 16; ++q)
        hg[q] = *reinterpret_cast<const uint2*>(hswz + (size_t)clx[q] * OC + c * 4);

    bf16x8 bwf[4], bwe[4];
    float bev[4];
#pragma unroll
    for (int nt = 0; nt < 4; ++nt) {
        int ch = nt * 16 + c;
        bwf[nt] = *reinterpret_cast<const bf16x8*>(WfT + ch * ED + g * 8);
        bwe[nt] = *reinterpret_cast<const bf16x8*>(WeT + ch * ED + g * 8);
        bev[nt] = be[ch];
    }

    float4 alo0 = reinterpret_cast<const float4*>(eattr + (size_t)erow0 * ED + g * 8)[0];
    float4 ahi0 = reinterpret_cast<const float4*>(eattr + (size_t)erow0 * ED + g * 8)[1];
    float4 alo1 = reinterpret_cast<const float4*>(eattr + (size_t)erow1 * ED + g * 8)[0];
    float4 ahi1 = reinterpret_cast<const float4*>(eattr + (size_t)erow1 * ED + g * 8)[1];
    float4 alo2 = reinterpret_cast<const float4*>(eattr + (size_t)erow2 * ED + g * 8)[0];
    float4 ahi2 = reinterpret_cast<const float4*>(eattr + (size_t)erow2 * ED + g * 8)[1];
    float4 alo3 = reinterpret_cast<const float4*>(eattr + (size_t)erow3 * ED + g * 8)[0];
    float4 ahi3 = reinterpret_cast<const float4*>(eattr + (size_t)erow3 * ED + g * 8)[1];

    bf16x8 afr[4];
    {
        union { bf16x8 v; unsigned d[4]; } pk;
#define PACKA(idx, lo, hi)                         \
        pk.d[0] = cvtpk(lo.x, lo.y);               \
        pk.d[1] = cvtpk(lo.z, lo.w);               \
        pk.d[2] = cvtpk(hi.x, hi.y);               \
        pk.d[3] = cvtpk(hi.z, hi.w);               \
        afr[idx] = pk.v;
        PACKA(0, alo0, ahi0)
        PACKA(1, alo1, ahi1)
        PACKA(2, alo2, ahi2)
        PACKA(3, alo3, ahi3)
#undef PACKA
    }

#pragma unroll
    for (int mt = 0; mt < 4; ++mt) {
        uint2 h0 = hg[mt * 4 + 0];
        uint2 h1 = hg[mt * 4 + 1];
        uint2 h2 = hg[mt * 4 + 2];
        uint2 h3 = hg[mt * 4 + 3];
        float sv[4][4];
#pragma unroll
        for (int nt = 0; nt < 4; ++nt) {
            f32x4 cz, ce;
            unsigned w0 = (nt < 2) ? h0.x : h0.y;
            unsigned w1 = (nt < 2) ? h1.x : h1.y;
            unsigned w2 = (nt < 2) ? h2.x : h2.y;
            unsigned w3 = (nt < 2) ? h3.x : h3.y;
            cz[0] = bf2f((unsigned short)((nt & 1) ? (w0 >> 16) : (w0 & 0xffffu)));
            cz[1] = bf2f((unsigned short)((nt & 1) ? (w1 >> 16) : (w1 & 0xffffu)));
            cz[2] = bf2f((unsigned short)((nt & 1) ? (w2 >> 16) : (w2 & 0xffffu)));
            cz[3] = bf2f((unsigned short)((nt & 1) ? (w3 >> 16) : (w3 & 0xffffu)));
            ce[0] = bev[nt]; ce[1] = bev[nt]; ce[2] = bev[nt]; ce[3] = bev[nt];
            f32x4 z  = __builtin_amdgcn_mfma_f32_16x16x32_bf16(afr[mt], bwf[nt], cz, 0, 0, 0);
            f32x4 ea = __builtin_amdgcn_mfma_f32_16x16x32_bf16(afr[mt], bwe[nt], ce, 0, 0, 0);
            sv[nt][0] = sigmoidf_(z[0]) * ea[0];
            sv[nt][1] = sigmoidf_(z[1]) * ea[1];
            sv[nt][2] = sigmoidf_(z[2]) * ea[2];
            sv[nt][3] = sigmoidf_(z[3]) * ea[3];
        }
#pragma unroll
        for (int r = 0; r < 4; ++r) {
            int row = tb + mt * 16 + g * 4 + r;
            uint2 pk;
            pk.x = cvtpk(sv[0][r], sv[1][r]);
            pk.y = cvtpk(sv[2][r], sv[3][r]);
            *reinterpret_cast<uint2*>(contrib + (size_t)row * OC + c * 4) = pk;
        }
    }
}

// K4-AT: atomic fallback.
extern "C" __global__ void __launch_bounds__(256, 3)
k_gate_at(const unsigned long long* __restrict__ ec, const float* __restrict__ eattr,
          const unsigned short* __restrict__ WfT, const unsigned short* __restrict__ WeT,
          const float* __restrict__ be, const unsigned short* __restrict__ hswz,
          float* __restrict__ agg) {
    int lane = threadIdx.x & 63;
    int w = threadIdx.x >> 6;
    int tb = (blockIdx.x * 4 + w) * 64;

    unsigned long long ev = ec[tb + lane];
    int e = (int)(ev & 0x3FFFFFFFULL);
    int cl = (int)((ev >> 30) & 0x1FFFFULL);
    int c = lane & 15, g = lane >> 4;

    int erow0 = __shfl(e, 0 * 16 + c);
    int erow1 = __shfl(e, 1 * 16 + c);
    int erow2 = __shfl(e, 2 * 16 + c);
    int erow3 = __shfl(e, 3 * 16 + c);
    int clx[16];
#pragma unroll
    for (int mt = 0; mt < 4; ++mt)
#pragma unroll
        for (int r = 0; r < 4; ++r)
            clx[mt * 4 + r] = __shfl(cl, mt * 16 + g * 4 + r);

    uint2 hg[16];
#pragma unroll
    for (int q = 0; q < 16; ++q)
        hg[q] = *reinterpret_cast<const uint2*>(hswz + (size_t)clx[q] * OC + c * 4);

    bf16x8 bwf[4], bwe[4];
    float bev[4];
#pragma unroll
    for (int nt = 0; nt < 4; ++nt) {
        int ch = nt * 16 + c;
        bwf[nt] = *reinterpret_cast<const bf16x8*>(WfT + ch * ED + g * 8);
        bwe[nt] = *reinterpret_cast<const bf16x8*>(WeT + ch * ED + g * 8);
        bev[nt] = be[ch];
    }

    float4 alo0 = reinterpret_cast<const float4*>(eattr + (size_t)erow0 * ED + g * 8)[0];
    float4 ahi0 = reinterpret_cast<const float4*>(eattr + (size_t)erow0 * ED + g * 8)[1];
    float4 alo1 = reinterpret_cast<const float4*>(eattr + (size_t)erow1 * ED + g * 8)[0];
    float4 ahi1 = reinterpret_cast<const float4*>(eattr + (size_t)erow1 * ED + g * 8)[1];
    float4 alo2 = reinterpret_cast<const float4*>(eattr + (size_t)erow2 * ED + g * 8)[0];
    float4 ahi2 = reinterpret_cast<const float4*>(eattr + (size_t)erow2 * ED + g * 8)[1];
    float4 alo3 = reinterpret_cast<const float4*>(eattr + (size_t)erow3 * ED + g * 8)[0];
    float4 ahi3 = reinterpret_cast<const float4*>(eattr + (size_t)erow3 * ED + g * 8)[1];

    bf16x8 afr[4];
    {
        union { bf16x8 v; unsigned d[4]; } pk;
#define PACKA(idx, lo, hi)                         \
        pk.d[0] = cvtpk(lo.x, lo.y);               \
        pk.d[1] = cvtpk(lo.z, lo.w);               \
        pk.d[2] = cvtpk(hi.x, hi.y);               \
        pk.d[3] = cvtpk(hi.z, hi.w);               \
        afr[idx] = pk.v;
        PACKA(0, alo0, ahi0)
        PACKA(1, alo1, ahi1)
        PACKA(2, alo2, ahi2)
        PACKA(3, alo3, ahi3)
#undef PACKA
    }

#pragma unroll
    for (int mt = 0; mt < 4; ++mt) {
        int cl0 = clx[mt * 4 + 0];
        int cl1 = clx[mt * 4 + 1];
        int cl2 = clx[mt * 4 + 2];
        int cl3 = clx[mt * 4 + 3];
        uint2 h0 = hg[mt * 4 + 0];
        uint2 h1 = hg[mt * 4 + 1];
        uint2 h2 = hg[mt * 4 + 2];
        uint2 h3 = hg[mt * 4 + 3];
#pragma unroll
        for (int nt = 0; nt < 4; ++nt) {
            int ch = nt * 16 + c;
            f32x4 cz, ce;
            unsigned w0 = (nt < 2) ? h0.x : h0.y;
            unsigned w1 = (nt < 2) ? h1.x : h1.y;
            unsigned w2 = (nt < 2) ? h2.x : h2.y;
            unsigned w3 = (nt < 2) ? h3.x : h3.y;
            cz[0] = bf2f((unsigned short)((nt & 1) ? (w0 >> 16) : (w0 & 0xffffu)));
            cz[1] = bf2f((unsigned short)((nt & 1) ? (w1 >> 16) : (w1 & 0xffffu)));
            cz[2] = bf2f((unsigned short)((nt & 1) ? (w2 >> 16) : (w2 & 0xffffu)));
            cz[3] = bf2f((unsigned short)((nt & 1) ? (w3 >> 16) : (w3 & 0xffffu)));
            ce[0] = bev[nt]; ce[1] = bev[nt]; ce[2] = bev[nt]; ce[3] = bev[nt];
            f32x4 z  = __builtin_amdgcn_mfma_f32_16x16x32_bf16(afr[mt], bwf[nt], cz, 0, 0, 0);
            f32x4 ea = __builtin_amdgcn_mfma_f32_16x16x32_bf16(afr[mt], bwe[nt], ce, 0, 0, 0);
            float c0 = sigmoidf_(z[0]) * ea[0];
            float c1 = sigmoidf_(z[1]) * ea[1];
            float c2 = sigmoidf_(z[2]) * ea[2];
            float c3 = sigmoidf_(z[3]) * ea[3];
            float s = c0;
            int t = cl0;
            if (cl1 != t) { atomicAdd(&agg[(size_t)t * OC + ch], s); s = 0.0f; t = cl1; }
            s += c1;
            if (cl2 != t) { atomicAdd(&agg[(size_t)t * OC + ch], s); s = 0.0f; t = cl2; }
            s += c2;
            if (cl3 != t) { atomicAdd(&agg[(size_t)t * OC + ch], s); s = 0.0f; t = cl3; }
            s += c3;
            atomicAdd(&agg[(size_t)t * OC + ch], s);
        }
    }
}

// K4b (NS): segmented sum of contrib + fused BN stats.
extern "C" __global__ void __launch_bounds__(256)
k_csumst(const unsigned short* __restrict__ contrib, const int* __restrict__ cur,
         float* __restrict__ agg, float* __restrict__ stats) {
    __shared__ float ls[256], lq[256];
    int w = threadIdx.x >> 6, c = threadIdx.x & 63;
    int ch = (c >> 2) + 16 * (c & 3);
    float sv = 0.0f, sq = 0.0f;
    for (int i = blockIdx.x * 4 + w; i < NN; i += 2048 * 4) {
        int start = (i == 0) ? 0 : cur[i - 1];
        int end = cur[i];
        float s = 0.0f;
        int p = start;
        for (; p + 7 < end; p += 8) {
            unsigned short u0 = contrib[(size_t)(p + 0) * OC + c];
            unsigned short u1 = contrib[(size_t)(p + 1) * OC + c];
            unsigned short u2 = contrib[(size_t)(p + 2) * OC + c];
            unsigned short u3 = contrib[(size_t)(p + 3) * OC + c];
            unsigned short u4 = contrib[(size_t)(p + 4) * OC + c];
            unsigned short u5 = contrib[(size_t)(p + 5) * OC + c];
            unsigned short u6 = contrib[(size_t)(p + 6) * OC + c];
            unsigned short u7 = contrib[(size_t)(p + 7) * OC + c];
            s += bf2f(u0); s += bf2f(u1); s += bf2f(u2); s += bf2f(u3);
            s += bf2f(u4); s += bf2f(u5); s += bf2f(u6); s += bf2f(u7);
        }
        for (; p < end; ++p) s += bf2f(contrib[(size_t)p * OC + c]);
        float v = agg[(size_t)i * OC + ch] + s;
        agg[(size_t)i * OC + ch] = v;
        sv += v;
        sq = fmaf(v, v, sq);
    }
    ls[threadIdx.x] = sv;
    lq[threadIdx.x] = sq;
    __syncthreads();
    if (threadIdx.x < 64) {
        float a = ls[c] + ls[c + 64] + ls[c + 128] + ls[c + 192];
        float b = lq[c] + lq[c + 64] + lq[c + 128] + lq[c + 192];
        atomicAdd(&stats[ch], a);
        atomicAdd(&stats[OC + ch], b);
    }
}

// K5: BN batch stats (AT path only).
extern "C" __global__ void __launch_bounds__(256)
k_stats(const float* __restrict__ a, float* __restrict__ stats) {
    __shared__ float ls[256], lq[256];
    int t = threadIdx.x;
    float s = 0.0f, q = 0.0f;
    for (size_t idx = (size_t)blockIdx.x * 256 + t; idx < (size_t)NN * OC;
         idx += (size_t)gridDim.x * 256) {
        float v = a[idx];
        s += v;
        q = fmaf(v, v, q);
    }
    ls[t] = s; lq[t] = q;
    __syncthreads();
    if (t < OC) {
        s = ls[t] + ls[t + 64] + ls[t + 128] + ls[t + 192];
        q = lq[t] + lq[t + 64] + lq[t + 128] + lq[t + 192];
        atomicAdd(&stats[t], s);
        atomicAdd(&stats[OC + t], q);
    }
}

// K6: BN normalize + residual(2x) + ReLU.
extern "C" __global__ void __launch_bounds__(256)
k_final(const float* __restrict__ a, const float* __restrict__ stats,
        const float* __restrict__ gamma, const float* __restrict__ beta,
        float* __restrict__ out) {
    size_t idx = (size_t)blockIdx.x * 256 + threadIdx.x;
    if (idx >= (size_t)NN * OC) return;
    int c = (int)(idx & 63);
    float mu = stats[c] * (1.0f / NN);
    float var = stats[OC + c] * (1.0f / NN) - mu * mu;
    float v = a[idx];
    float y = fmaf(gamma[c] * (v - mu), rsqrtf(var + 1e-5f), beta[c]);
    out[idx] = fmaxf(2.0f * y, 0.0f);
}

extern "C" void kernel_launch(void* const* d_in, const int* in_sizes, int n_in,
                              void* d_out, int out_size, void* d_ws, size_t ws_size,
                              hipStream_t stream) {
    const float* x     = (const float*)d_in[0];
    const int*   ei    = (const int*)d_in[1];   // (2, NE) int32
    const float* eattr = (const float*)d_in[2];
    const float* Wl    = (const float*)d_in[3];
    const float* bl    = (const float*)d_in[4];
    const float* Wr    = (const float*)d_in[5];
    const float* We    = (const float*)d_in[6];
    const float* be    = (const float*)d_in[7];
    const float* Wg    = (const float*)d_in[8];
    const float* bg    = (const float*)d_in[9];
    const float* gamma = (const float*)d_in[10];
    const float* beta  = (const float*)d_in[11];
    float* out = (float*)d_out;

    float* agg = (float*)d_ws;
    unsigned short* ybf   = (unsigned short*)(agg + (size_t)NN * OC);
    unsigned short* xwrbf = ybf + (size_t)NN * OC;   // becomes hswz after k_aggoh
    unsigned long long* ec = (unsigned long long*)(xwrbf + (size_t)NN * OC);
    int* cur   = (int*)(ec + (size_t)NE);
    int* bsum  = cur + NN;
    float* stats = (float*)(bsum + 128);
    unsigned short* WfT  = (unsigned short*)(stats + 128);
    unsigned short* WeT  = WfT + ED * OC;
    unsigned short* WlrT = WeT + ED * OC;
    float* hb = (float*)(WlrT + 2 * INC * OC);
    int* gcur256 = (int*)(hb + OC);
    unsigned short* contrib = (unsigned short*)(gcur256 + 256);
    unsigned long long* ecp =
        (unsigned long long*)(((size_t)contrib + 7) & ~(size_t)7);
    unsigned short* hswz = xwrbf;

    size_t base_bytes = (size_t)((char*)contrib - (char*)d_ws);
    bool ns = ws_size >= base_bytes + 8 + (size_t)NE * OC * sizeof(unsigned short);

    const int* rowv = ei;
    const int* colv = ei + NE;

    hipMemsetAsync(cur, 0, NN * sizeof(int), stream);
    hipMemsetAsync(stats, 0, 2 * OC * sizeof(float), stream);

    k_wfuse<<<(2 * ED * OC + OC + 2 * INC * OC + 255) / 256, 256, 0, stream>>>(
        We, be, Wg, Wl, Wr, WfT, WeT, hb, WlrT);
    k_xw<<<(NN + 63) / 64, 256, 0, stream>>>(x, WlrT, ybf, xwrbf, colv, cur);
    k_scanA<<<98, 1024, 0, stream>>>(cur, cur, bsum);
    k_scanB<<<1, 128, 0, stream>>>(bsum);
    k_scanC<<<98, 1024, 0, stream>>>(cur, bsum);
    if (ns) {
        k_init256<<<1, 256, 0, stream>>>(cur, gcur256);
        k_coarse<<<(NE + 2047) / 2048, 256, 0, stream>>>(colv, rowv, gcur256, ecp);
        k_fine<<<(NE + 255) / 256, 256, 0, stream>>>(ecp, cur, ec);
    } else {
        k_bucket<<<(NE + 255) / 256, 256, 0, stream>>>(colv, rowv, cur, ec);
    }
    k_aggoh<<<(NN + 3) / 4, 256, 0, stream>>>(ec, cur, ybf, xwrbf, bl, Wg, bg, hb, agg);
    if (ns) {
        k_gate_ns<<<NE / 256, 256, 0, stream>>>(ec, eattr, WfT, WeT, be, hswz, contrib);
        k_csumst<<<2048, 256, 0, stream>>>(contrib, cur, agg, stats);
    } else {
        k_gate_at<<<NE / 256, 256, 0, stream>>>(ec, eattr, WfT, WeT, be, hswz, agg);
        k_stats<<<2048, 256, 0, stream>>>(agg, stats);
    }
    k_final<<<((size_t)NN * OC + 255) / 256, 256, 0, stream>>>(agg, stats, gamma, beta, out);
}